// Round 14
// baseline (590.169 us; speedup 1.0000x reference)
//
#include <hip/hip_runtime.h>
#include <hip/hip_bf16.h>
#include <math.h>

typedef short v8s __attribute__((ext_vector_type(8)));
typedef float v4f __attribute__((ext_vector_type(4)));
typedef unsigned int v4u __attribute__((ext_vector_type(4)));
typedef unsigned short us;
typedef unsigned int uu;

#define MFMA16(a,b,c) __builtin_amdgcn_mfma_f32_16x16x32_bf16((a),(b),(c),0,0,0)

// ---------------- workspace layout (fragment-linear, permuted-k) ----------
// Permutation (chunk t): slot (g,i) holds logical k = 32t + 16*(i>>2) + 4g + (i&3).
// Layer N's D registers repack in-lane into layer N+1's B-fragment.
#define W3F_ELEMS (7*13*512)
#define W2F_ELEMS (13*512)
#define W4F_ELEMS (14*512)
#define WALL_ELEMS (W3F_ELEMS + W2F_ELEMS + W4F_ELEMS)   // 60416 -> 120832 B
#define OFF_W3F 0
#define OFF_W2F (OFF_W3F + W3F_ELEMS*2)
#define OFF_W4F (OFF_W2F + W2F_ELEMS*2)
#define OFF_B2B (OFF_W4F + W4F_ELEMS*2)
#define OFF_B3B (OFF_B2B + 208*4)
#define OFF_B4B (OFF_B3B + 224*4)
#define OFF_W5B (OFF_B4B + 32*4)
#define OFF_W1P (OFF_W5B + 32*4)   // [96] f32: w1x[32] | w1y[32] | b1p[32]
// constants staged to LDS: [b2 208 | b3 224 | b4 32 | w5 32 | w1p 96]
#define CB_ELEMS 592
#define CB_B3 208
#define CB_B4 432
#define CB_W5 464
#define CB_W1 496

__device__ __forceinline__ us f2bf(float f) {
    union { float f; unsigned int u; } v; v.f = f;
    unsigned int u = v.u + 0x7FFFu + ((v.u >> 16) & 1u);   // RNE
    return (us)(u >> 16);
}
__device__ __forceinline__ uu pack2bf(float a, float b) {
    union { __hip_bfloat162 v; uu u; } cv;
    cv.v.x = __float2bfloat16(a);
    cv.v.y = __float2bfloat16(b);
    return cv.u;
}

// ---------------- prep: fp32 weights -> bf16 fragment layout in ws --------
__global__ void prep_kernel(const float* __restrict__ w1, const float* __restrict__ b1,
                            const float* __restrict__ w2, const float* __restrict__ w3,
                            const float* __restrict__ w4, const float* __restrict__ b2,
                            const float* __restrict__ b3, const float* __restrict__ b4,
                            const float* __restrict__ w5, char* __restrict__ ws) {
    us* w3f = (us*)(ws + OFF_W3F);
    us* w2f = (us*)(ws + OFF_W2F);
    us* w4f = (us*)(ws + OFF_W4F);
    float* b2b = (float*)(ws + OFF_B2B);
    float* b3b = (float*)(ws + OFF_B3B);
    float* b4b = (float*)(ws + OFF_B4B);
    float* w5b = (float*)(ws + OFF_W5B);
    float* w1p = (float*)(ws + OFF_W1P);

    const int gid = blockIdx.x * blockDim.x + threadIdx.x;
    const int stride = gridDim.x * blockDim.x;

    for (int idx = gid; idx < W3F_ELEMS; idx += stride) {
        int i = idx & 7, lane = (idx >> 3) & 63, f = idx >> 9;
        int nt3 = f % 13, t = f / 13;
        int cc = lane & 15, gg = lane >> 4;
        int j = 16*nt3 + cc;
        int k = 32*t + 16*(i >> 2) + 4*gg + (i & 3);    // permuted-k
        w3f[idx] = f2bf((j < 200 && k < 200) ? w3[j*200 + k] : 0.f);
    }
    for (int idx = gid; idx < W2F_ELEMS; idx += stride) {
        int i = idx & 7, lane = (idx >> 3) & 63, nt = idx >> 9;
        int j = 16*nt + (lane & 15), k = 8*(lane >> 4) + i;   // standard k
        w2f[idx] = f2bf((j < 200 && k < 20) ? w2[j*20 + k] : 0.f);
    }
    for (int idx = gid; idx < W4F_ELEMS; idx += stride) {
        int i = idx & 7, lane = (idx >> 3) & 63, f = idx >> 9;
        int t = f >> 1, jt = f & 1;
        int cc = lane & 15, gg = lane >> 4;
        int j = 16*jt + cc;
        int k = 32*t + 16*(i >> 2) + 4*gg + (i & 3);    // permuted-k
        w4f[idx] = f2bf((j < 20 && k < 200) ? w4[j*200 + k] : 0.f);
    }
    for (int i = gid; i < 208; i += stride) b2b[i] = (i < 200) ? b2[i] : 0.f;
    for (int i = gid; i < 224; i += stride) b3b[i] = (i < 200) ? b3[i] : 0.f;
    for (int i = gid; i < 32;  i += stride) b4b[i] = (i < 20) ? b4[i] : 0.f;
    for (int i = gid; i < 32;  i += stride) w5b[i] = (i < 20) ? w5[i] : 0.f;
    for (int i = gid; i < 96;  i += stride) {
        int q = i >> 5, r = i & 31;
        float v = 0.f;
        if (r < 20) v = (q == 0) ? w1[2*r] : (q == 1) ? w1[2*r + 1] : b1[r];
        w1p[i] = v;
    }
}

// ---- compact half-gather: 100 rows of ONE table, 4 accumulators, ~25 regs -
__device__ __forceinline__ float gather_half(
    const int* __restrict__ nrow, const float* __restrict__ emb, int lane)
{
    float a0=0.f, a1=0.f, a2=0.f, a3=0.f;
    #pragma unroll 2
    for (int k = 0; k < 96; k += 8) {
        int4 i0 = *(const int4*)(nrow + k);       // wave-uniform -> s_load
        int4 i1 = *(const int4*)(nrow + k + 4);
        a0 += emb[(size_t)i0.x*64 + lane];        // coalesced 256-B rows
        a1 += emb[(size_t)i0.y*64 + lane];
        a2 += emb[(size_t)i0.z*64 + lane];
        a3 += emb[(size_t)i0.w*64 + lane];
        a0 += emb[(size_t)i1.x*64 + lane];
        a1 += emb[(size_t)i1.y*64 + lane];
        a2 += emb[(size_t)i1.z*64 + lane];
        a3 += emb[(size_t)i1.w*64 + lane];
    }
    int4 it = *(const int4*)(nrow + 96);
    a0 += emb[(size_t)it.x*64 + lane];
    a1 += emb[(size_t)it.y*64 + lane];
    a2 += emb[(size_t)it.z*64 + lane];
    a3 += emb[(size_t)it.w*64 + lane];
    return (a0+a1)+(a2+a3);
}

// ---- layer 1 (2->20) for all 4 m-tiles (e = 16m + c), into B-frag regs ----
__device__ __forceinline__ void make_b1f4(float su, float si, int c, int g,
                                          const float* __restrict__ w1p,
                                          v4u b1f[4])
{
    const v4f wx0 = *(const v4f*)(w1p + 8*g);
    const v4f wx1 = *(const v4f*)(w1p + 8*g + 4);
    const v4f wy0 = *(const v4f*)(w1p + 32 + 8*g);
    const v4f wy1 = *(const v4f*)(w1p + 32 + 8*g + 4);
    const v4f wb0 = *(const v4f*)(w1p + 64 + 8*g);
    const v4f wb1 = *(const v4f*)(w1p + 64 + 8*g + 4);
    #pragma unroll
    for (int m = 0; m < 4; ++m) {
        const float xu = __shfl(su, 16*m + c);
        const float xv = __shfl(si, 16*m + c);
        float h0 = fmaxf(fmaf(xu, wx0[0], fmaf(xv, wy0[0], wb0[0])), 0.f);
        float h1 = fmaxf(fmaf(xu, wx0[1], fmaf(xv, wy0[1], wb0[1])), 0.f);
        float h2 = fmaxf(fmaf(xu, wx0[2], fmaf(xv, wy0[2], wb0[2])), 0.f);
        float h3 = fmaxf(fmaf(xu, wx0[3], fmaf(xv, wy0[3], wb0[3])), 0.f);
        float h4 = fmaxf(fmaf(xu, wx1[0], fmaf(xv, wy1[0], wb1[0])), 0.f);
        float h5 = fmaxf(fmaf(xu, wx1[1], fmaf(xv, wy1[1], wb1[1])), 0.f);
        float h6 = fmaxf(fmaf(xu, wx1[2], fmaf(xv, wy1[2], wb1[2])), 0.f);
        float h7 = fmaxf(fmaf(xu, wx1[3], fmaf(xv, wy1[3], wb1[3])), 0.f);
        b1f[m] = (v4u){ pack2bf(h0,h1), pack2bf(h2,h3),
                        pack2bf(h4,h5), pack2bf(h6,h7) };
    }
}

// ---------------- fused MLP kernel: m=4 + in-loop fenced gather ------------
// Persistent: 256 blocks x 8 waves; weights + constants in LDS (staged once).
// Wave = independent worker: one batch row (all 64 e) per iteration, doing
// its OWN next-row gather in sched_barrier-fenced blocks between layer 2 and
// layer 3 -- fences keep the gather's ~25-reg transient state from inflating
// the MFMA-phase register peak (r9/r10 spilled without them), while the
// SIMD-mate wave's MFMA phase covers the gather latency.
__global__ __launch_bounds__(512, 2) void mlp_kernel(
    const int* __restrict__ user_idxs, const int* __restrict__ item_idxs,
    const int* __restrict__ uidx, const int* __restrict__ iidx,
    const float* __restrict__ uemb, const float* __restrict__ iemb,
    const float* __restrict__ b5p, const char* __restrict__ ws,
    float* __restrict__ out, int B, int NIT)
{
    __shared__ us wall[WALL_ELEMS];                // 120832 B : w3f | w2f | w4f
    __shared__ __align__(16) float cbuf[CB_ELEMS]; //   2368 B : biases + w1p

    const int tid  = (int)threadIdx.x;
    const int lane = tid & 63;
    const int wv   = __builtin_amdgcn_readfirstlane(tid >> 6);
    const int c = lane & 15;
    const int g = lane >> 4;
    const int wstep = (int)gridDim.x * 8;          // batch rows per iteration

    // ---- stage weights + constants to LDS once ----------------------------
    {
        const us* src = (const us*)(ws + OFF_W3F);
        for (int s = tid; s < WALL_ELEMS/8; s += 512)
            *(v8s*)(wall + s*8) = *(const v8s*)(src + s*8);
        const float* csrc = (const float*)(ws + OFF_B2B);
        for (int s = tid; s < CB_ELEMS; s += 512)
            cbuf[s] = csrc[s];
    }
    const us* w3l = wall;
    const us* w2l = wall + W3F_ELEMS;
    const us* w4l = wall + W3F_ELEMS + W2F_ELEMS;
    const float b5v = b5p[0];

    // ---- gather iteration 0 (own wave's batch row) -------------------------
    int b = (int)blockIdx.x*8 + wv;
    int bc = (b < B) ? b : (B - 1);
    float su = gather_half(uidx + (size_t)user_idxs[bc]*100, uemb, lane);
    float si = gather_half(iidx + (size_t)item_idxs[bc]*100, iemb, lane);
    __syncthreads();                               // weights staged (only barrier)

    #pragma unroll 1
    for (int it = 0; it < NIT; ++it) {
        const int nb = b + wstep;
        const int nbc = (nb < B) ? nb : (B - 1);
        const bool more = (it + 1 < NIT);

        // ---- Layer 1: all 4 m-tiles (covers e = 0..63); su/si die here ------
        v4u b1f[4];
        make_b1f4(su, si, c, g, cbuf + CB_W1, b1f);

        // ---- Layer 2 (20->200): each A-read-pair feeds 4 m MFMAs ------------
        v4u b2f[4][7];
        #pragma unroll
        for (int t = 0; t < 6; ++t) {
            v8s afa = *(const v8s*)(w2l + ((2*t)*64   + lane)*8);
            v8s afb = *(const v8s*)(w2l + ((2*t+1)*64 + lane)*8);
            v4f bva = *(const v4f*)(cbuf + 32*t + 4*g);
            v4f bvb = *(const v4f*)(cbuf + 32*t + 16 + 4*g);
            #pragma unroll
            for (int m = 0; m < 4; ++m) {
                v8s bb = __builtin_bit_cast(v8s, b1f[m]);
                v4f aa = MFMA16(afa, bb, bva);
                v4f ab = MFMA16(afb, bb, bvb);
                b2f[m][t] = (v4u){ pack2bf(fmaxf(aa[0],0.f), fmaxf(aa[1],0.f)),
                                   pack2bf(fmaxf(aa[2],0.f), fmaxf(aa[3],0.f)),
                                   pack2bf(fmaxf(ab[0],0.f), fmaxf(ab[1],0.f)),
                                   pack2bf(fmaxf(ab[2],0.f), fmaxf(ab[3],0.f)) };
            }
        }
        {   // t = 6: nt = 12 only; upper k-half zero (pad)
            v8s afa = *(const v8s*)(w2l + (12*64 + lane)*8);
            v4f bva = *(const v4f*)(cbuf + 192 + 4*g);
            #pragma unroll
            for (int m = 0; m < 4; ++m) {
                v8s bb = __builtin_bit_cast(v8s, b1f[m]);
                v4f aa = MFMA16(afa, bb, bva);
                b2f[m][6] = (v4u){ pack2bf(fmaxf(aa[0],0.f), fmaxf(aa[1],0.f)),
                                   pack2bf(fmaxf(aa[2],0.f), fmaxf(aa[3],0.f)),
                                   0u, 0u };
            }
        }

        // ---- fenced gather of next row (user half, then item half) ----------
        // sched_barrier(0) walls keep gather transients out of MFMA regions.
        __builtin_amdgcn_sched_barrier(0);
        float nsu = 0.f, nsi = 0.f;
        if (more) nsu = gather_half(uidx + (size_t)user_idxs[nbc]*100, uemb, lane);
        __builtin_amdgcn_sched_barrier(0);
        if (more) nsi = gather_half(iidx + (size_t)item_idxs[nbc]*100, iemb, lane);
        __builtin_amdgcn_sched_barrier(0);

        // ---- Layers 3+4 fused at nt-pair granularity ------------------------
        v4f acc4[4][2];
        v4f bc0 = *(const v4f*)(cbuf + CB_B4 + 4*g);
        v4f bc1 = *(const v4f*)(cbuf + CB_B4 + 16 + 4*g);
        #pragma unroll
        for (int p = 0; p < 7; ++p) {
            v8s a40 = *(const v8s*)(w4l + ((2*p)*64   + lane)*8);
            v8s a41 = *(const v8s*)(w4l + ((2*p+1)*64 + lane)*8);

            v4f acc3[4][2];
            {   // ksc = 0, bias as C-in
                v8s af0 = *(const v8s*)(w3l + ((2*p)*64 + lane)*8);
                v4f bv0 = *(const v4f*)(cbuf + CB_B3 + 16*(2*p) + 4*g);
                #pragma unroll
                for (int m = 0; m < 4; ++m)
                    acc3[m][0] = MFMA16(af0, __builtin_bit_cast(v8s, b2f[m][0]), bv0);
                if (p < 6) {
                    v8s af1 = *(const v8s*)(w3l + ((2*p+1)*64 + lane)*8);
                    v4f bv1 = *(const v4f*)(cbuf + CB_B3 + 16*(2*p+1) + 4*g);
                    #pragma unroll
                    for (int m = 0; m < 4; ++m)
                        acc3[m][1] = MFMA16(af1, __builtin_bit_cast(v8s, b2f[m][0]), bv1);
                }
            }
            #pragma unroll
            for (int ksc = 1; ksc < 7; ++ksc) {
                v8s af0 = *(const v8s*)(w3l + ((ksc*13 + 2*p)*64 + lane)*8);
                #pragma unroll
                for (int m = 0; m < 4; ++m)
                    acc3[m][0] = MFMA16(af0, __builtin_bit_cast(v8s, b2f[m][ksc]), acc3[m][0]);
                if (p < 6) {
                    v8s af1 = *(const v8s*)(w3l + ((ksc*13 + 2*p+1)*64 + lane)*8);
                    #pragma unroll
                    for (int m = 0; m < 4; ++m)
                        acc3[m][1] = MFMA16(af1, __builtin_bit_cast(v8s, b2f[m][ksc]), acc3[m][1]);
                }
            }
            // repack + layer-4 MFMAs (acc3 dies here; w4f rows >= 20 are zero,
            // and at p=6 the upper 16 k-slots are zero-padded)
            #pragma unroll
            for (int m = 0; m < 4; ++m) {
                v4u bfu;
                if (p < 6) {
                    bfu = (v4u){
                        pack2bf(fmaxf(acc3[m][0][0],0.f), fmaxf(acc3[m][0][1],0.f)),
                        pack2bf(fmaxf(acc3[m][0][2],0.f), fmaxf(acc3[m][0][3],0.f)),
                        pack2bf(fmaxf(acc3[m][1][0],0.f), fmaxf(acc3[m][1][1],0.f)),
                        pack2bf(fmaxf(acc3[m][1][2],0.f), fmaxf(acc3[m][1][3],0.f)) };
                } else {
                    bfu = (v4u){
                        pack2bf(fmaxf(acc3[m][0][0],0.f), fmaxf(acc3[m][0][1],0.f)),
                        pack2bf(fmaxf(acc3[m][0][2],0.f), fmaxf(acc3[m][0][3],0.f)),
                        0u, 0u };
                }
                v8s bb = __builtin_bit_cast(v8s, bfu);
                acc4[m][0] = MFMA16(a40, bb, (p == 0) ? bc0 : acc4[m][0]);
                acc4[m][1] = MFMA16(a41, bb, (p == 0) ? bc1 : acc4[m][1]);
            }
        }

        __builtin_amdgcn_sched_barrier(0);   // fence: iteration state dies here

        // ---- Layer 5 (20->1) + mean over E=64 + sigmoid ----------------------
        v4f w5lo = *(const v4f*)(cbuf + CB_W5 + 4*g);
        v4f w5hi = *(const v4f*)(cbuf + CB_W5 + 16 + 4*g);
        float s = 0.f;
        #pragma unroll
        for (int m = 0; m < 4; ++m) {
            #pragma unroll
            for (int q = 0; q < 4; ++q) {
                float h0 = fmaxf(acc4[m][0][q], 0.f);   // bias already in acc
                float h1 = fmaxf(acc4[m][1][q], 0.f);
                s = fmaf(h0, w5lo[q], fmaf(h1, w5hi[q], s));
            }
        }
        #pragma unroll
        for (int off = 1; off < 64; off <<= 1) s += __shfl_xor(s, off);
        if (lane == 0 && b < B)
            out[b] = 1.0f / (1.0f + expf(-(s * (1.0f / 64.0f) + b5v)));

        su = nsu; si = nsi; b = nb;
    }
}

extern "C" void kernel_launch(void* const* d_in, const int* in_sizes, int n_in,
                              void* d_out, int out_size, void* d_ws, size_t ws_size,
                              hipStream_t stream) {
    const int*   user_idxs = (const int*)d_in[0];
    const int*   item_idxs = (const int*)d_in[1];
    const int*   uidx      = (const int*)d_in[2];
    const int*   iidx      = (const int*)d_in[3];
    const float* uemb      = (const float*)d_in[4];
    const float* iemb      = (const float*)d_in[5];
    const float* w1 = (const float*)d_in[6];
    const float* b1 = (const float*)d_in[7];
    const float* w2 = (const float*)d_in[8];
    const float* b2 = (const float*)d_in[9];
    const float* w3 = (const float*)d_in[10];
    const float* b3 = (const float*)d_in[11];
    const float* w4 = (const float*)d_in[12];
    const float* b4 = (const float*)d_in[13];
    const float* w5 = (const float*)d_in[14];
    const float* b5 = (const float*)d_in[15];
    float* out = (float*)d_out;
    char* ws = (char*)d_ws;

    const int B = in_sizes[0];

    hipLaunchKernelGGL(prep_kernel, dim3(256), dim3(256), 0, stream,
                       w1, b1, w2, w3, w4, b2, b3, b4, w5, ws);

    const int GRID = 256;
    const int rows_per_iter = GRID * 8;
    const int NIT = (B + rows_per_iter - 1) / rows_per_iter;
    hipLaunchKernelGGL(mlp_kernel, dim3(GRID), dim3(512), 0, stream,
                       user_idxs, item_idxs, uidx, iidx, uemb, iemb,
                       b5, ws, out, B, NIT);
}

// Round 15
// 423.550 us; speedup vs baseline: 1.3934x; 1.3934x over previous
//
#include <hip/hip_runtime.h>
#include <hip/hip_bf16.h>
#include <math.h>

typedef short v8s __attribute__((ext_vector_type(8)));
typedef float v4f __attribute__((ext_vector_type(4)));
typedef unsigned int v4u __attribute__((ext_vector_type(4)));
typedef unsigned short us;
typedef unsigned int uu;

#define MFMA16(a,b,c) __builtin_amdgcn_mfma_f32_16x16x32_bf16((a),(b),(c),0,0,0)

// ---------------- workspace layout (fragment-linear, permuted-k) ----------
// Permutation (chunk t): slot (g,i) holds logical k = 32t + 16*(i>>2) + 4g + (i&3).
// Layer N's D registers repack in-lane into layer N+1's B-fragment.
#define W3F_ELEMS (7*13*512)
#define W2F_ELEMS (13*512)
#define W4F_ELEMS (14*512)
#define WALL_ELEMS (W3F_ELEMS + W2F_ELEMS + W4F_ELEMS)   // 60416 -> 120832 B
#define OFF_W3F 0
#define OFF_W2F (OFF_W3F + W3F_ELEMS*2)
#define OFF_W4F (OFF_W2F + W2F_ELEMS*2)
#define OFF_B2B (OFF_W4F + W4F_ELEMS*2)
#define OFF_B3B (OFF_B2B + 208*4)
#define OFF_B4B (OFF_B3B + 224*4)
#define OFF_W5B (OFF_B4B + 32*4)
#define OFF_W1P (OFF_W5B + 32*4)   // [96] f32: w1x[32] | w1y[32] | b1p[32]
#define OFF_X   (256*1024)         // x_u[B*64] f32 | x_i[B*64] f32
// constants staged to LDS: [b2 208 | b3 224 | b4 32 | w5 32 | w1p 96]
#define CB_ELEMS 592
#define CB_B3 208
#define CB_B4 432
#define CB_W5 464
#define CB_W1 496

__device__ __forceinline__ us f2bf(float f) {
    union { float f; unsigned int u; } v; v.f = f;
    unsigned int u = v.u + 0x7FFFu + ((v.u >> 16) & 1u);   // RNE
    return (us)(u >> 16);
}
__device__ __forceinline__ uu pack2bf(float a, float b) {
    union { __hip_bfloat162 v; uu u; } cv;
    cv.v.x = __float2bfloat16(a);
    cv.v.y = __float2bfloat16(b);
    return cv.u;
}

// ---------------- gather kernel (memory-regime) + fused weight prep --------
// One wave per (batch row, table): 64 lanes read full 256-B embedding rows
// (coalesced), 8 accumulators -> ~32 loads in flight. Low VGPR, no LDS ->
// 8 waves/SIMD. Blocks < 256 additionally run the (tiny) weight-prep after
// their gather task, removing the separate prep launch.
__global__ __launch_bounds__(256, 8) void gather_kernel(
    const int* __restrict__ user_idxs, const int* __restrict__ item_idxs,
    const int* __restrict__ uidx, const int* __restrict__ iidx,
    const float* __restrict__ uemb, const float* __restrict__ iemb,
    const float* __restrict__ w1, const float* __restrict__ b1,
    const float* __restrict__ w2, const float* __restrict__ w3,
    const float* __restrict__ w4, const float* __restrict__ b2,
    const float* __restrict__ b3, const float* __restrict__ b4,
    const float* __restrict__ w5, char* __restrict__ ws,
    float* __restrict__ xu, float* __restrict__ xi, int B)
{
    const int tid  = (int)threadIdx.x;
    const int lane = tid & 63;
    const int task = (int)blockIdx.x * 4 + (tid >> 6);

    if (task < 2*B) {
        const int b = task >> 1;
        const bool isItem = task & 1;
        const int* nrow = isItem ? (iidx + (size_t)item_idxs[b]*100)
                                 : (uidx + (size_t)user_idxs[b]*100);
        const float* emb = isItem ? iemb : uemb;

        float a0=0.f,a1=0.f,a2=0.f,a3=0.f,a4=0.f,a5=0.f,a6=0.f,a7=0.f;
        #pragma unroll 2
        for (int k = 0; k < 96; k += 16) {        // 6 rounds x 16 rows
            int4 i0 = *(const int4*)(nrow + k);
            int4 i1 = *(const int4*)(nrow + k + 4);
            int4 i2 = *(const int4*)(nrow + k + 8);
            int4 i3 = *(const int4*)(nrow + k + 12);
            a0 += emb[(size_t)i0.x*64 + lane];
            a1 += emb[(size_t)i0.y*64 + lane];
            a2 += emb[(size_t)i0.z*64 + lane];
            a3 += emb[(size_t)i0.w*64 + lane];
            a4 += emb[(size_t)i1.x*64 + lane];
            a5 += emb[(size_t)i1.y*64 + lane];
            a6 += emb[(size_t)i1.z*64 + lane];
            a7 += emb[(size_t)i1.w*64 + lane];
            a0 += emb[(size_t)i2.x*64 + lane];
            a1 += emb[(size_t)i2.y*64 + lane];
            a2 += emb[(size_t)i2.z*64 + lane];
            a3 += emb[(size_t)i2.w*64 + lane];
            a4 += emb[(size_t)i3.x*64 + lane];
            a5 += emb[(size_t)i3.y*64 + lane];
            a6 += emb[(size_t)i3.z*64 + lane];
            a7 += emb[(size_t)i3.w*64 + lane];
        }
        int4 it = *(const int4*)(nrow + 96);       // rows 96..99
        a0 += emb[(size_t)it.x*64 + lane];
        a1 += emb[(size_t)it.y*64 + lane];
        a2 += emb[(size_t)it.z*64 + lane];
        a3 += emb[(size_t)it.w*64 + lane];

        float s = ((a0+a4)+(a1+a5)) + ((a2+a6)+(a3+a7));
        (isItem ? xi : xu)[(size_t)b*64 + lane] = s;   // coalesced 256-B store
    }

    // ---- fused weight prep (blocks 0..255 only; ~1 elem per thread) -------
    if (blockIdx.x < 256) {
        us* w3f = (us*)(ws + OFF_W3F);
        us* w2f = (us*)(ws + OFF_W2F);
        us* w4f = (us*)(ws + OFF_W4F);
        float* b2b = (float*)(ws + OFF_B2B);
        float* b3b = (float*)(ws + OFF_B3B);
        float* b4b = (float*)(ws + OFF_B4B);
        float* w5b = (float*)(ws + OFF_W5B);
        float* w1p = (float*)(ws + OFF_W1P);

        const int gid = (int)blockIdx.x * 256 + tid;
        const int stride = 256 * 256;

        for (int idx = gid; idx < W3F_ELEMS; idx += stride) {
            int i = idx & 7, ln = (idx >> 3) & 63, f = idx >> 9;
            int nt3 = f % 13, t = f / 13;
            int cc = ln & 15, gg = ln >> 4;
            int j = 16*nt3 + cc;
            int k = 32*t + 16*(i >> 2) + 4*gg + (i & 3);    // permuted-k
            w3f[idx] = f2bf((j < 200 && k < 200) ? w3[j*200 + k] : 0.f);
        }
        for (int idx = gid; idx < W2F_ELEMS; idx += stride) {
            int i = idx & 7, ln = (idx >> 3) & 63, nt = idx >> 9;
            int j = 16*nt + (ln & 15), k = 8*(ln >> 4) + i;   // standard k
            w2f[idx] = f2bf((j < 200 && k < 20) ? w2[j*20 + k] : 0.f);
        }
        for (int idx = gid; idx < W4F_ELEMS; idx += stride) {
            int i = idx & 7, ln = (idx >> 3) & 63, f = idx >> 9;
            int t = f >> 1, jt = f & 1;
            int cc = ln & 15, gg = ln >> 4;
            int j = 16*jt + cc;
            int k = 32*t + 16*(i >> 2) + 4*gg + (i & 3);    // permuted-k
            w4f[idx] = f2bf((j < 20 && k < 200) ? w4[j*200 + k] : 0.f);
        }
        for (int i = gid; i < 208; i += stride) b2b[i] = (i < 200) ? b2[i] : 0.f;
        for (int i = gid; i < 224; i += stride) b3b[i] = (i < 200) ? b3[i] : 0.f;
        for (int i = gid; i < 32;  i += stride) b4b[i] = (i < 20) ? b4[i] : 0.f;
        for (int i = gid; i < 32;  i += stride) w5b[i] = (i < 20) ? w5[i] : 0.f;
        for (int i = gid; i < 96;  i += stride) {
            int q = i >> 5, r = i & 31;
            float v = 0.f;
            if (r < 20) v = (q == 0) ? w1[2*r] : (q == 1) ? w1[2*r + 1] : b1[r];
            w1p[i] = v;
        }
    }
}

// ---- layer 1 (2->20) for all 4 m-tiles (e = 16m + c), into B-frag regs ----
__device__ __forceinline__ void make_b1f4(float su, float si, int c, int g,
                                          const float* __restrict__ w1p,
                                          v4u b1f[4])
{
    const v4f wx0 = *(const v4f*)(w1p + 8*g);
    const v4f wx1 = *(const v4f*)(w1p + 8*g + 4);
    const v4f wy0 = *(const v4f*)(w1p + 32 + 8*g);
    const v4f wy1 = *(const v4f*)(w1p + 32 + 8*g + 4);
    const v4f wb0 = *(const v4f*)(w1p + 64 + 8*g);
    const v4f wb1 = *(const v4f*)(w1p + 64 + 8*g + 4);
    #pragma unroll
    for (int m = 0; m < 4; ++m) {
        const float xu = __shfl(su, 16*m + c);
        const float xv = __shfl(si, 16*m + c);
        float h0 = fmaxf(fmaf(xu, wx0[0], fmaf(xv, wy0[0], wb0[0])), 0.f);
        float h1 = fmaxf(fmaf(xu, wx0[1], fmaf(xv, wy0[1], wb0[1])), 0.f);
        float h2 = fmaxf(fmaf(xu, wx0[2], fmaf(xv, wy0[2], wb0[2])), 0.f);
        float h3 = fmaxf(fmaf(xu, wx0[3], fmaf(xv, wy0[3], wb0[3])), 0.f);
        float h4 = fmaxf(fmaf(xu, wx1[0], fmaf(xv, wy1[0], wb1[0])), 0.f);
        float h5 = fmaxf(fmaf(xu, wx1[1], fmaf(xv, wy1[1], wb1[1])), 0.f);
        float h6 = fmaxf(fmaf(xu, wx1[2], fmaf(xv, wy1[2], wb1[2])), 0.f);
        float h7 = fmaxf(fmaf(xu, wx1[3], fmaf(xv, wy1[3], wb1[3])), 0.f);
        b1f[m] = (v4u){ pack2bf(h0,h1), pack2bf(h2,h3),
                        pack2bf(h4,h5), pack2bf(h6,h7) };
    }
}

// ---------------- MLP kernel: m=4 single pass, layer3/4 fused by nt-pair ---
// Persistent: 256 blocks x 8 waves; weights + constants in LDS (staged once).
// Wave = independent worker: one batch row (all 64 e) per iteration; x comes
// from ws (gather kernel output) via 2 coalesced loads. s_setprio(1) around
// the MFMA clusters (T5): independent waves drift out of phase, so the
// MFMA-phase wave wins issue slots over its VALU-phase SIMD-mate.
__global__ __launch_bounds__(512, 2) void mlp_kernel(
    const float* __restrict__ xu, const float* __restrict__ xi,
    const float* __restrict__ b5p, const char* __restrict__ ws,
    float* __restrict__ out, int B, int NIT)
{
    __shared__ us wall[WALL_ELEMS];                // 120832 B : w3f | w2f | w4f
    __shared__ __align__(16) float cbuf[CB_ELEMS]; //   2368 B : biases + w1p

    const int tid  = (int)threadIdx.x;
    const int lane = tid & 63;
    const int wv   = __builtin_amdgcn_readfirstlane(tid >> 6);
    const int c = lane & 15;
    const int g = lane >> 4;
    const int wstep = (int)gridDim.x * 8;          // batch rows per iteration

    // ---- stage weights + constants to LDS once ----------------------------
    {
        const us* src = (const us*)(ws + OFF_W3F);
        for (int s = tid; s < WALL_ELEMS/8; s += 512)
            *(v8s*)(wall + s*8) = *(const v8s*)(src + s*8);
        const float* csrc = (const float*)(ws + OFF_B2B);
        for (int s = tid; s < CB_ELEMS; s += 512)
            cbuf[s] = csrc[s];
    }
    const us* w3l = wall;
    const us* w2l = wall + W3F_ELEMS;
    const us* w4l = wall + W3F_ELEMS + W2F_ELEMS;
    const float b5v = b5p[0];

    int b = (int)blockIdx.x*8 + wv;
    int bc = (b < B) ? b : (B - 1);
    float su = xu[(size_t)bc*64 + lane];
    float si = xi[(size_t)bc*64 + lane];
    __syncthreads();                               // weights staged (only barrier)

    #pragma unroll 1
    for (int it = 0; it < NIT; ++it) {
        const int nb = b + wstep;
        const int nbc = (nb < B) ? nb : (B - 1);
        const bool more = (it + 1 < NIT);

        // ---- Layer 1: all 4 m-tiles (covers e = 0..63) ----------------------
        v4u b1f[4];
        make_b1f4(su, si, c, g, cbuf + CB_W1, b1f);

        // ---- Layer 2 (20->200): each A-read-pair feeds 4 m MFMAs ------------
        v4u b2f[4][7];
        __builtin_amdgcn_s_setprio(1);
        #pragma unroll
        for (int t = 0; t < 6; ++t) {
            v8s afa = *(const v8s*)(w2l + ((2*t)*64   + lane)*8);
            v8s afb = *(const v8s*)(w2l + ((2*t+1)*64 + lane)*8);
            v4f bva = *(const v4f*)(cbuf + 32*t + 4*g);
            v4f bvb = *(const v4f*)(cbuf + 32*t + 16 + 4*g);
            #pragma unroll
            for (int m = 0; m < 4; ++m) {
                v8s bb = __builtin_bit_cast(v8s, b1f[m]);
                v4f aa = MFMA16(afa, bb, bva);
                v4f ab = MFMA16(afb, bb, bvb);
                b2f[m][t] = (v4u){ pack2bf(fmaxf(aa[0],0.f), fmaxf(aa[1],0.f)),
                                   pack2bf(fmaxf(aa[2],0.f), fmaxf(aa[3],0.f)),
                                   pack2bf(fmaxf(ab[0],0.f), fmaxf(ab[1],0.f)),
                                   pack2bf(fmaxf(ab[2],0.f), fmaxf(ab[3],0.f)) };
            }
        }
        {   // t = 6: nt = 12 only; upper k-half zero (pad)
            v8s afa = *(const v8s*)(w2l + (12*64 + lane)*8);
            v4f bva = *(const v4f*)(cbuf + 192 + 4*g);
            #pragma unroll
            for (int m = 0; m < 4; ++m) {
                v8s bb = __builtin_bit_cast(v8s, b1f[m]);
                v4f aa = MFMA16(afa, bb, bva);
                b2f[m][6] = (v4u){ pack2bf(fmaxf(aa[0],0.f), fmaxf(aa[1],0.f)),
                                   pack2bf(fmaxf(aa[2],0.f), fmaxf(aa[3],0.f)),
                                   0u, 0u };
            }
        }
        __builtin_amdgcn_s_setprio(0);

        // ---- prefetch next iteration's x (hidden under layer-3/4 MFMAs) ----
        float nsu = 0.f, nsi = 0.f;
        if (more) {
            nsu = xu[(size_t)nbc*64 + lane];
            nsi = xi[(size_t)nbc*64 + lane];
        }

        // ---- Layers 3+4 fused at nt-pair granularity ------------------------
        // p-th pass: acc3[4 m][2 nt] over all 7 k-chunks (bias C-in at ksc=0),
        // repack -> layer-4 B-frag (k-chunk p), feed acc4 (bias C-in at p=0).
        v4f acc4[4][2];
        v4f bc0 = *(const v4f*)(cbuf + CB_B4 + 4*g);
        v4f bc1 = *(const v4f*)(cbuf + CB_B4 + 16 + 4*g);
        #pragma unroll
        for (int p = 0; p < 7; ++p) {
            v8s a40 = *(const v8s*)(w4l + ((2*p)*64   + lane)*8);
            v8s a41 = *(const v8s*)(w4l + ((2*p+1)*64 + lane)*8);

            v4f acc3[4][2];
            __builtin_amdgcn_s_setprio(1);
            {   // ksc = 0, bias as C-in
                v8s af0 = *(const v8s*)(w3l + ((2*p)*64 + lane)*8);
                v4f bv0 = *(const v4f*)(cbuf + CB_B3 + 16*(2*p) + 4*g);
                #pragma unroll
                for (int m = 0; m < 4; ++m)
                    acc3[m][0] = MFMA16(af0, __builtin_bit_cast(v8s, b2f[m][0]), bv0);
                if (p < 6) {
                    v8s af1 = *(const v8s*)(w3l + ((2*p+1)*64 + lane)*8);
                    v4f bv1 = *(const v4f*)(cbuf + CB_B3 + 16*(2*p+1) + 4*g);
                    #pragma unroll
                    for (int m = 0; m < 4; ++m)
                        acc3[m][1] = MFMA16(af1, __builtin_bit_cast(v8s, b2f[m][0]), bv1);
                }
            }
            #pragma unroll
            for (int ksc = 1; ksc < 7; ++ksc) {
                v8s af0 = *(const v8s*)(w3l + ((ksc*13 + 2*p)*64 + lane)*8);
                #pragma unroll
                for (int m = 0; m < 4; ++m)
                    acc3[m][0] = MFMA16(af0, __builtin_bit_cast(v8s, b2f[m][ksc]), acc3[m][0]);
                if (p < 6) {
                    v8s af1 = *(const v8s*)(w3l + ((ksc*13 + 2*p+1)*64 + lane)*8);
                    #pragma unroll
                    for (int m = 0; m < 4; ++m)
                        acc3[m][1] = MFMA16(af1, __builtin_bit_cast(v8s, b2f[m][ksc]), acc3[m][1]);
                }
            }
            __builtin_amdgcn_s_setprio(0);
            // repack + layer-4 MFMAs (acc3 dies here; w4f rows >= 20 are zero,
            // and at p=6 the upper 16 k-slots are zero-padded)
            #pragma unroll
            for (int m = 0; m < 4; ++m) {
                v4u bfu;
                if (p < 6) {
                    bfu = (v4u){
                        pack2bf(fmaxf(acc3[m][0][0],0.f), fmaxf(acc3[m][0][1],0.f)),
                        pack2bf(fmaxf(acc3[m][0][2],0.f), fmaxf(acc3[m][0][3],0.f)),
                        pack2bf(fmaxf(acc3[m][1][0],0.f), fmaxf(acc3[m][1][1],0.f)),
                        pack2bf(fmaxf(acc3[m][1][2],0.f), fmaxf(acc3[m][1][3],0.f)) };
                } else {
                    bfu = (v4u){
                        pack2bf(fmaxf(acc3[m][0][0],0.f), fmaxf(acc3[m][0][1],0.f)),
                        pack2bf(fmaxf(acc3[m][0][2],0.f), fmaxf(acc3[m][0][3],0.f)),
                        0u, 0u };
                }
                v8s bb = __builtin_bit_cast(v8s, bfu);
                acc4[m][0] = MFMA16(a40, bb, (p == 0) ? bc0 : acc4[m][0]);
                acc4[m][1] = MFMA16(a41, bb, (p == 0) ? bc1 : acc4[m][1]);
            }
        }

        __builtin_amdgcn_sched_barrier(0);   // fence: iteration state dies here

        // ---- Layer 5 (20->1) + mean over E=64 + sigmoid ----------------------
        v4f w5lo = *(const v4f*)(cbuf + CB_W5 + 4*g);
        v4f w5hi = *(const v4f*)(cbuf + CB_W5 + 16 + 4*g);
        float s = 0.f;
        #pragma unroll
        for (int m = 0; m < 4; ++m) {
            #pragma unroll
            for (int q = 0; q < 4; ++q) {
                float h0 = fmaxf(acc4[m][0][q], 0.f);   // bias already in acc
                float h1 = fmaxf(acc4[m][1][q], 0.f);
                s = fmaf(h0, w5lo[q], fmaf(h1, w5hi[q], s));
            }
        }
        #pragma unroll
        for (int off = 1; off < 64; off <<= 1) s += __shfl_xor(s, off);
        if (lane == 0 && b < B)
            out[b] = 1.0f / (1.0f + expf(-(s * (1.0f / 64.0f) + b5v)));

        su = nsu; si = nsi; b = nb;
    }
}

extern "C" void kernel_launch(void* const* d_in, const int* in_sizes, int n_in,
                              void* d_out, int out_size, void* d_ws, size_t ws_size,
                              hipStream_t stream) {
    const int*   user_idxs = (const int*)d_in[0];
    const int*   item_idxs = (const int*)d_in[1];
    const int*   uidx      = (const int*)d_in[2];
    const int*   iidx      = (const int*)d_in[3];
    const float* uemb      = (const float*)d_in[4];
    const float* iemb      = (const float*)d_in[5];
    const float* w1 = (const float*)d_in[6];
    const float* b1 = (const float*)d_in[7];
    const float* w2 = (const float*)d_in[8];
    const float* b2 = (const float*)d_in[9];
    const float* w3 = (const float*)d_in[10];
    const float* b3 = (const float*)d_in[11];
    const float* w4 = (const float*)d_in[12];
    const float* b4 = (const float*)d_in[13];
    const float* w5 = (const float*)d_in[14];
    const float* b5 = (const float*)d_in[15];
    float* out = (float*)d_out;
    char* ws = (char*)d_ws;

    const int B = in_sizes[0];
    float* xu = (float*)(ws + OFF_X);
    float* xi = xu + (size_t)B * 64;

    const int ntask = 2 * B;                       // (b, table) wave-tasks
    hipLaunchKernelGGL(gather_kernel, dim3((ntask + 3) / 4), dim3(256), 0, stream,
                       user_idxs, item_idxs, uidx, iidx, uemb, iemb,
                       w1, b1, w2, w3, w4, b2, b3, b4, w5, ws, xu, xi, B);

    const int GRID = 256;
    const int rows_per_iter = GRID * 8;
    const int NIT = (B + rows_per_iter - 1) / rows_per_iter;
    hipLaunchKernelGGL(mlp_kernel, dim3(GRID), dim3(512), 0, stream,
                       xu, xi, b5, ws, out, B, NIT);
}

// Round 16
// 326.623 us; speedup vs baseline: 1.8069x; 1.2968x over previous
//
#include <hip/hip_runtime.h>
#include <hip/hip_bf16.h>
#include <math.h>

typedef short v8s __attribute__((ext_vector_type(8)));
typedef float v4f __attribute__((ext_vector_type(4)));
typedef unsigned int v4u __attribute__((ext_vector_type(4)));
typedef unsigned short us;
typedef unsigned int uu;

#define MFMA16(a,b,c) __builtin_amdgcn_mfma_f32_16x16x32_bf16((a),(b),(c),0,0,0)

// ---------------- workspace layout (fragment-linear, permuted-k) ----------
// Permutation (chunk t): slot (g,i) holds logical k = 32t + 16*(i>>2) + 4g + (i&3).
// Layer N's D registers repack in-lane into layer N+1's B-fragment.
#define W3F_ELEMS (7*13*512)
#define W2F_ELEMS (13*512)
#define W4F_ELEMS (14*512)
#define WALL_ELEMS (W3F_ELEMS + W2F_ELEMS + W4F_ELEMS)   // 60416 -> 120832 B
#define OFF_W3F 0
#define OFF_W2F (OFF_W3F + W3F_ELEMS*2)
#define OFF_W4F (OFF_W2F + W2F_ELEMS*2)
#define OFF_B2B (OFF_W4F + W4F_ELEMS*2)
#define OFF_B3B (OFF_B2B + 208*4)
#define OFF_B4B (OFF_B3B + 224*4)
#define OFF_W5B (OFF_B4B + 32*4)
#define OFF_W1P (OFF_W5B + 32*4)   // [96] f32: w1x[32] | w1y[32] | b1p[32]
#define OFF_X   (256*1024)         // x_u[B*64] f32 | x_i[B*64] f32 | fp16 tables
// constants staged to LDS: [b2 208 | b3 224 | b4 32 | w5 32 | w1p 96]
#define CB_ELEMS 592
#define CB_B3 208
#define CB_B4 432
#define CB_W5 464
#define CB_W1 496

__device__ __forceinline__ us f2bf(float f) {
    union { float f; unsigned int u; } v; v.f = f;
    unsigned int u = v.u + 0x7FFFu + ((v.u >> 16) & 1u);   // RNE
    return (us)(u >> 16);
}
__device__ __forceinline__ uu pack2bf(float a, float b) {
    union { __hip_bfloat162 v; uu u; } cv;
    cv.v.x = __float2bfloat16(a);
    cv.v.y = __float2bfloat16(b);
    return cv.u;
}
__device__ __forceinline__ us f2h(float f) {
    _Float16 h = (_Float16)f;                              // RNE
    return *(us*)&h;
}

// ---------------- prep+conv: weights->bf16 frags, embeddings->fp16 --------
__global__ void prep_conv_kernel(
    const float* __restrict__ w1, const float* __restrict__ b1,
    const float* __restrict__ w2, const float* __restrict__ w3,
    const float* __restrict__ w4, const float* __restrict__ b2,
    const float* __restrict__ b3, const float* __restrict__ b4,
    const float* __restrict__ w5, char* __restrict__ ws,
    const float* __restrict__ uemb, const float* __restrict__ iemb,
    _Float16* __restrict__ ue16, _Float16* __restrict__ ie16,
    int nu64, int ni64)
{
    us* w3f = (us*)(ws + OFF_W3F);
    us* w2f = (us*)(ws + OFF_W2F);
    us* w4f = (us*)(ws + OFF_W4F);
    float* b2b = (float*)(ws + OFF_B2B);
    float* b3b = (float*)(ws + OFF_B3B);
    float* b4b = (float*)(ws + OFF_B4B);
    float* w5b = (float*)(ws + OFF_W5B);
    float* w1p = (float*)(ws + OFF_W1P);

    const int gid = blockIdx.x * blockDim.x + threadIdx.x;
    const int stride = gridDim.x * blockDim.x;

    // ---- embedding tables f32 -> fp16, 4-wide (counts are multiples of 64) -
    for (int i = gid*4; i < nu64; i += stride*4) {
        float4 v = *(const float4*)(uemb + i);
        ushort4 o = { f2h(v.x), f2h(v.y), f2h(v.z), f2h(v.w) };
        *(ushort4*)((us*)ue16 + i) = o;
    }
    for (int i = gid*4; i < ni64; i += stride*4) {
        float4 v = *(const float4*)(iemb + i);
        ushort4 o = { f2h(v.x), f2h(v.y), f2h(v.z), f2h(v.w) };
        *(ushort4*)((us*)ie16 + i) = o;
    }

    // ---- weight fragment prep ---------------------------------------------
    for (int idx = gid; idx < W3F_ELEMS; idx += stride) {
        int i = idx & 7, lane = (idx >> 3) & 63, f = idx >> 9;
        int nt3 = f % 13, t = f / 13;
        int cc = lane & 15, gg = lane >> 4;
        int j = 16*nt3 + cc;
        int k = 32*t + 16*(i >> 2) + 4*gg + (i & 3);    // permuted-k
        w3f[idx] = f2bf((j < 200 && k < 200) ? w3[j*200 + k] : 0.f);
    }
    for (int idx = gid; idx < W2F_ELEMS; idx += stride) {
        int i = idx & 7, lane = (idx >> 3) & 63, nt = idx >> 9;
        int j = 16*nt + (lane & 15), k = 8*(lane >> 4) + i;   // standard k
        w2f[idx] = f2bf((j < 200 && k < 20) ? w2[j*20 + k] : 0.f);
    }
    for (int idx = gid; idx < W4F_ELEMS; idx += stride) {
        int i = idx & 7, lane = (idx >> 3) & 63, f = idx >> 9;
        int t = f >> 1, jt = f & 1;
        int cc = lane & 15, gg = lane >> 4;
        int j = 16*jt + cc;
        int k = 32*t + 16*(i >> 2) + 4*gg + (i & 3);    // permuted-k
        w4f[idx] = f2bf((j < 20 && k < 200) ? w4[j*200 + k] : 0.f);
    }
    for (int i = gid; i < 208; i += stride) b2b[i] = (i < 200) ? b2[i] : 0.f;
    for (int i = gid; i < 224; i += stride) b3b[i] = (i < 200) ? b3[i] : 0.f;
    for (int i = gid; i < 32;  i += stride) b4b[i] = (i < 20) ? b4[i] : 0.f;
    for (int i = gid; i < 32;  i += stride) w5b[i] = (i < 20) ? w5[i] : 0.f;
    for (int i = gid; i < 96;  i += stride) {
        int q = i >> 5, r = i & 31;
        float v = 0.f;
        if (r < 20) v = (q == 0) ? w1[2*r] : (q == 1) ? w1[2*r + 1] : b1[r];
        w1p[i] = v;
    }
}

// ---------------- gather kernel: memory-regime, fp16 rows ------------------
// One wave per (batch row, table): 64 lanes read 128-B fp16 embedding rows
// (coalesced), 8 accumulators -> ~32 loads in flight; sums in f32.
__global__ __launch_bounds__(256, 8) void gather_kernel(
    const int* __restrict__ user_idxs, const int* __restrict__ item_idxs,
    const int* __restrict__ uidx, const int* __restrict__ iidx,
    const _Float16* __restrict__ ue16, const _Float16* __restrict__ ie16,
    float* __restrict__ xu, float* __restrict__ xi, int B)
{
    const int tid  = (int)threadIdx.x;
    const int lane = tid & 63;
    const int task = (int)blockIdx.x * 4 + (tid >> 6);
    if (task >= 2*B) return;
    const int b = task >> 1;
    const bool isItem = task & 1;

    const int* nrow = isItem ? (iidx + (size_t)item_idxs[b]*100)
                             : (uidx + (size_t)user_idxs[b]*100);
    const _Float16* emb = isItem ? ie16 : ue16;

    float a0=0.f,a1=0.f,a2=0.f,a3=0.f,a4=0.f,a5=0.f,a6=0.f,a7=0.f;
    #pragma unroll 2
    for (int k = 0; k < 96; k += 16) {            // 6 rounds x 16 rows
        int4 i0 = *(const int4*)(nrow + k);       // wave-uniform -> s_load
        int4 i1 = *(const int4*)(nrow + k + 4);
        int4 i2 = *(const int4*)(nrow + k + 8);
        int4 i3 = *(const int4*)(nrow + k + 12);
        a0 += (float)emb[(size_t)i0.x*64 + lane]; // coalesced 128-B rows
        a1 += (float)emb[(size_t)i0.y*64 + lane];
        a2 += (float)emb[(size_t)i0.z*64 + lane];
        a3 += (float)emb[(size_t)i0.w*64 + lane];
        a4 += (float)emb[(size_t)i1.x*64 + lane];
        a5 += (float)emb[(size_t)i1.y*64 + lane];
        a6 += (float)emb[(size_t)i1.z*64 + lane];
        a7 += (float)emb[(size_t)i1.w*64 + lane];
        a0 += (float)emb[(size_t)i2.x*64 + lane];
        a1 += (float)emb[(size_t)i2.y*64 + lane];
        a2 += (float)emb[(size_t)i2.z*64 + lane];
        a3 += (float)emb[(size_t)i2.w*64 + lane];
        a4 += (float)emb[(size_t)i3.x*64 + lane];
        a5 += (float)emb[(size_t)i3.y*64 + lane];
        a6 += (float)emb[(size_t)i3.z*64 + lane];
        a7 += (float)emb[(size_t)i3.w*64 + lane];
    }
    int4 it = *(const int4*)(nrow + 96);           // rows 96..99
    a0 += (float)emb[(size_t)it.x*64 + lane];
    a1 += (float)emb[(size_t)it.y*64 + lane];
    a2 += (float)emb[(size_t)it.z*64 + lane];
    a3 += (float)emb[(size_t)it.w*64 + lane];

    float s = ((a0+a4)+(a1+a5)) + ((a2+a6)+(a3+a7));
    (isItem ? xi : xu)[(size_t)b*64 + lane] = s;   // coalesced 256-B store
}

// ---- layer 1 (2->20) for all 4 m-tiles (e = 16m + c), into B-frag regs ----
__device__ __forceinline__ void make_b1f4(float su, float si, int c, int g,
                                          const float* __restrict__ w1p,
                                          v4u b1f[4])
{
    const v4f wx0 = *(const v4f*)(w1p + 8*g);
    const v4f wx1 = *(const v4f*)(w1p + 8*g + 4);
    const v4f wy0 = *(const v4f*)(w1p + 32 + 8*g);
    const v4f wy1 = *(const v4f*)(w1p + 32 + 8*g + 4);
    const v4f wb0 = *(const v4f*)(w1p + 64 + 8*g);
    const v4f wb1 = *(const v4f*)(w1p + 64 + 8*g + 4);
    #pragma unroll
    for (int m = 0; m < 4; ++m) {
        const float xu = __shfl(su, 16*m + c);
        const float xv = __shfl(si, 16*m + c);
        float h0 = fmaxf(fmaf(xu, wx0[0], fmaf(xv, wy0[0], wb0[0])), 0.f);
        float h1 = fmaxf(fmaf(xu, wx0[1], fmaf(xv, wy0[1], wb0[1])), 0.f);
        float h2 = fmaxf(fmaf(xu, wx0[2], fmaf(xv, wy0[2], wb0[2])), 0.f);
        float h3 = fmaxf(fmaf(xu, wx0[3], fmaf(xv, wy0[3], wb0[3])), 0.f);
        float h4 = fmaxf(fmaf(xu, wx1[0], fmaf(xv, wy1[0], wb1[0])), 0.f);
        float h5 = fmaxf(fmaf(xu, wx1[1], fmaf(xv, wy1[1], wb1[1])), 0.f);
        float h6 = fmaxf(fmaf(xu, wx1[2], fmaf(xv, wy1[2], wb1[2])), 0.f);
        float h7 = fmaxf(fmaf(xu, wx1[3], fmaf(xv, wy1[3], wb1[3])), 0.f);
        b1f[m] = (v4u){ pack2bf(h0,h1), pack2bf(h2,h3),
                        pack2bf(h4,h5), pack2bf(h6,h7) };
    }
}

// ---------------- MLP kernel: m=4 single pass, layer3/4 fused by nt-pair ---
// (unchanged from round 15: 250 us, MfmaUtil 45%, no spill)
__global__ __launch_bounds__(512, 2) void mlp_kernel(
    const float* __restrict__ xu, const float* __restrict__ xi,
    const float* __restrict__ b5p, const char* __restrict__ ws,
    float* __restrict__ out, int B, int NIT)
{
    __shared__ us wall[WALL_ELEMS];                // 120832 B : w3f | w2f | w4f
    __shared__ __align__(16) float cbuf[CB_ELEMS]; //   2368 B : biases + w1p

    const int tid  = (int)threadIdx.x;
    const int lane = tid & 63;
    const int wv   = __builtin_amdgcn_readfirstlane(tid >> 6);
    const int c = lane & 15;
    const int g = lane >> 4;
    const int wstep = (int)gridDim.x * 8;          // batch rows per iteration

    // ---- stage weights + constants to LDS once ----------------------------
    {
        const us* src = (const us*)(ws + OFF_W3F);
        for (int s = tid; s < WALL_ELEMS/8; s += 512)
            *(v8s*)(wall + s*8) = *(const v8s*)(src + s*8);
        const float* csrc = (const float*)(ws + OFF_B2B);
        for (int s = tid; s < CB_ELEMS; s += 512)
            cbuf[s] = csrc[s];
    }
    const us* w3l = wall;
    const us* w2l = wall + W3F_ELEMS;
    const us* w4l = wall + W3F_ELEMS + W2F_ELEMS;
    const float b5v = b5p[0];

    int b = (int)blockIdx.x*8 + wv;
    int bc = (b < B) ? b : (B - 1);
    float su = xu[(size_t)bc*64 + lane];
    float si = xi[(size_t)bc*64 + lane];
    __syncthreads();                               // weights staged (only barrier)

    #pragma unroll 1
    for (int it = 0; it < NIT; ++it) {
        const int nb = b + wstep;
        const int nbc = (nb < B) ? nb : (B - 1);
        const bool more = (it + 1 < NIT);

        // ---- Layer 1: all 4 m-tiles (covers e = 0..63) ----------------------
        v4u b1f[4];
        make_b1f4(su, si, c, g, cbuf + CB_W1, b1f);

        // ---- Layer 2 (20->200): each A-read-pair feeds 4 m MFMAs ------------
        v4u b2f[4][7];
        __builtin_amdgcn_s_setprio(1);
        #pragma unroll
        for (int t = 0; t < 6; ++t) {
            v8s afa = *(const v8s*)(w2l + ((2*t)*64   + lane)*8);
            v8s afb = *(const v8s*)(w2l + ((2*t+1)*64 + lane)*8);
            v4f bva = *(const v4f*)(cbuf + 32*t + 4*g);
            v4f bvb = *(const v4f*)(cbuf + 32*t + 16 + 4*g);
            #pragma unroll
            for (int m = 0; m < 4; ++m) {
                v8s bb = __builtin_bit_cast(v8s, b1f[m]);
                v4f aa = MFMA16(afa, bb, bva);
                v4f ab = MFMA16(afb, bb, bvb);
                b2f[m][t] = (v4u){ pack2bf(fmaxf(aa[0],0.f), fmaxf(aa[1],0.f)),
                                   pack2bf(fmaxf(aa[2],0.f), fmaxf(aa[3],0.f)),
                                   pack2bf(fmaxf(ab[0],0.f), fmaxf(ab[1],0.f)),
                                   pack2bf(fmaxf(ab[2],0.f), fmaxf(ab[3],0.f)) };
            }
        }
        {   // t = 6: nt = 12 only; upper k-half zero (pad)
            v8s afa = *(const v8s*)(w2l + (12*64 + lane)*8);
            v4f bva = *(const v4f*)(cbuf + 192 + 4*g);
            #pragma unroll
            for (int m = 0; m < 4; ++m) {
                v8s bb = __builtin_bit_cast(v8s, b1f[m]);
                v4f aa = MFMA16(afa, bb, bva);
                b2f[m][6] = (v4u){ pack2bf(fmaxf(aa[0],0.f), fmaxf(aa[1],0.f)),
                                   pack2bf(fmaxf(aa[2],0.f), fmaxf(aa[3],0.f)),
                                   0u, 0u };
            }
        }
        __builtin_amdgcn_s_setprio(0);

        // ---- prefetch next iteration's x (hidden under layer-3/4 MFMAs) ----
        float nsu = 0.f, nsi = 0.f;
        if (more) {
            nsu = xu[(size_t)nbc*64 + lane];
            nsi = xi[(size_t)nbc*64 + lane];
        }

        // ---- Layers 3+4 fused at nt-pair granularity ------------------------
        v4f acc4[4][2];
        v4f bc0 = *(const v4f*)(cbuf + CB_B4 + 4*g);
        v4f bc1 = *(const v4f*)(cbuf + CB_B4 + 16 + 4*g);
        #pragma unroll
        for (int p = 0; p < 7; ++p) {
            v8s a40 = *(const v8s*)(w4l + ((2*p)*64   + lane)*8);
            v8s a41 = *(const v8s*)(w4l + ((2*p+1)*64 + lane)*8);

            v4f acc3[4][2];
            __builtin_amdgcn_s_setprio(1);
            {   // ksc = 0, bias as C-in
                v8s af0 = *(const v8s*)(w3l + ((2*p)*64 + lane)*8);
                v4f bv0 = *(const v4f*)(cbuf + CB_B3 + 16*(2*p) + 4*g);
                #pragma unroll
                for (int m = 0; m < 4; ++m)
                    acc3[m][0] = MFMA16(af0, __builtin_bit_cast(v8s, b2f[m][0]), bv0);
                if (p < 6) {
                    v8s af1 = *(const v8s*)(w3l + ((2*p+1)*64 + lane)*8);
                    v4f bv1 = *(const v4f*)(cbuf + CB_B3 + 16*(2*p+1) + 4*g);
                    #pragma unroll
                    for (int m = 0; m < 4; ++m)
                        acc3[m][1] = MFMA16(af1, __builtin_bit_cast(v8s, b2f[m][0]), bv1);
                }
            }
            #pragma unroll
            for (int ksc = 1; ksc < 7; ++ksc) {
                v8s af0 = *(const v8s*)(w3l + ((ksc*13 + 2*p)*64 + lane)*8);
                #pragma unroll
                for (int m = 0; m < 4; ++m)
                    acc3[m][0] = MFMA16(af0, __builtin_bit_cast(v8s, b2f[m][ksc]), acc3[m][0]);
                if (p < 6) {
                    v8s af1 = *(const v8s*)(w3l + ((ksc*13 + 2*p+1)*64 + lane)*8);
                    #pragma unroll
                    for (int m = 0; m < 4; ++m)
                        acc3[m][1] = MFMA16(af1, __builtin_bit_cast(v8s, b2f[m][ksc]), acc3[m][1]);
                }
            }
            __builtin_amdgcn_s_setprio(0);
            // repack + layer-4 MFMAs (acc3 dies here)
            #pragma unroll
            for (int m = 0; m < 4; ++m) {
                v4u bfu;
                if (p < 6) {
                    bfu = (v4u){
                        pack2bf(fmaxf(acc3[m][0][0],0.f), fmaxf(acc3[m][0][1],0.f)),
                        pack2bf(fmaxf(acc3[m][0][2],0.f), fmaxf(acc3[m][0][3],0.f)),
                        pack2bf(fmaxf(acc3[m][1][0],0.f), fmaxf(acc3[m][1][1],0.f)),
                        pack2bf(fmaxf(acc3[m][1][2],0.f), fmaxf(acc3[m][1][3],0.f)) };
                } else {
                    bfu = (v4u){
                        pack2bf(fmaxf(acc3[m][0][0],0.f), fmaxf(acc3[m][0][1],0.f)),
                        pack2bf(fmaxf(acc3[m][0][2],0.f), fmaxf(acc3[m][0][3],0.f)),
                        0u, 0u };
                }
                v8s bb = __builtin_bit_cast(v8s, bfu);
                acc4[m][0] = MFMA16(a40, bb, (p == 0) ? bc0 : acc4[m][0]);
                acc4[m][1] = MFMA16(a41, bb, (p == 0) ? bc1 : acc4[m][1]);
            }
        }

        __builtin_amdgcn_sched_barrier(0);   // fence: iteration state dies here

        // ---- Layer 5 (20->1) + mean over E=64 + sigmoid ----------------------
        v4f w5lo = *(const v4f*)(cbuf + CB_W5 + 4*g);
        v4f w5hi = *(const v4f*)(cbuf + CB_W5 + 16 + 4*g);
        float s = 0.f;
        #pragma unroll
        for (int m = 0; m < 4; ++m) {
            #pragma unroll
            for (int q = 0; q < 4; ++q) {
                float h0 = fmaxf(acc4[m][0][q], 0.f);   // bias already in acc
                float h1 = fmaxf(acc4[m][1][q], 0.f);
                s = fmaf(h0, w5lo[q], fmaf(h1, w5hi[q], s));
            }
        }
        #pragma unroll
        for (int off = 1; off < 64; off <<= 1) s += __shfl_xor(s, off);
        if (lane == 0 && b < B)
            out[b] = 1.0f / (1.0f + expf(-(s * (1.0f / 64.0f) + b5v)));

        su = nsu; si = nsi; b = nb;
    }
}

extern "C" void kernel_launch(void* const* d_in, const int* in_sizes, int n_in,
                              void* d_out, int out_size, void* d_ws, size_t ws_size,
                              hipStream_t stream) {
    const int*   user_idxs = (const int*)d_in[0];
    const int*   item_idxs = (const int*)d_in[1];
    const int*   uidx      = (const int*)d_in[2];
    const int*   iidx      = (const int*)d_in[3];
    const float* uemb      = (const float*)d_in[4];
    const float* iemb      = (const float*)d_in[5];
    const float* w1 = (const float*)d_in[6];
    const float* b1 = (const float*)d_in[7];
    const float* w2 = (const float*)d_in[8];
    const float* b2 = (const float*)d_in[9];
    const float* w3 = (const float*)d_in[10];
    const float* b3 = (const float*)d_in[11];
    const float* w4 = (const float*)d_in[12];
    const float* b4 = (const float*)d_in[13];
    const float* w5 = (const float*)d_in[14];
    const float* b5 = (const float*)d_in[15];
    float* out = (float*)d_out;
    char* ws = (char*)d_ws;

    const int B    = in_sizes[0];
    const int nu64 = in_sizes[4];   // N_USERS * 64
    const int ni64 = in_sizes[5];   // N_ITEMS * 64

    float* xu = (float*)(ws + OFF_X);
    float* xi = xu + (size_t)B * 64;
    _Float16* ue16 = (_Float16*)(ws + OFF_X + (size_t)2 * B * 64 * 4);
    _Float16* ie16 = ue16 + nu64;

    hipLaunchKernelGGL(prep_conv_kernel, dim3(1024), dim3(256), 0, stream,
                       w1, b1, w2, w3, w4, b2, b3, b4, w5, ws,
                       uemb, iemb, ue16, ie16, nu64, ni64);

    const int ntask = 2 * B;                       // (b, table) wave-tasks
    hipLaunchKernelGGL(gather_kernel, dim3((ntask + 3) / 4), dim3(256), 0, stream,
                       user_idxs, item_idxs, uidx, iidx, ue16, ie16, xu, xi, B);

    const int GRID = 256;
    const int rows_per_iter = GRID * 8;
    const int NIT = (B + rows_per_iter - 1) / rows_per_iter;
    hipLaunchKernelGGL(mlp_kernel, dim3(GRID), dim3(512), 0, stream,
                       xu, xi, b5, ws, out, B, NIT);
}